// Round 1
// baseline (2510.673 us; speedup 1.0000x reference)
//
#include <hip/hip_runtime.h>

#define NB 2
#define CIN 3
#define HH 512
#define WW 512
#define C2 64
#define HP 514   // padded input for mode pool
#define HM 504   // mode-pool output size

// ---------------- K1: quantize + pad -> u8 bins [2,3,514,514] ----------------
__global__ __launch_bounds__(256) void k_quant(const float* __restrict__ x,
                                               unsigned char* __restrict__ bins) {
  int idx = blockIdx.x * 256 + threadIdx.x;
  const int total = NB * CIN * HP * HP;
  if (idx >= total) return;
  int xp = idx % HP;
  int t  = idx / HP;
  int yp = t % HP;
  int bc = t / HP;
  unsigned char v = 0;
  if (xp >= 1 && xp <= WW && yp >= 1 && yp <= HH) {
    float val = x[(bc * HH + (yp - 1)) * WW + (xp - 1)];
    float q = rintf((val * 255.0f) / 16.0f);   // matches jnp.round(x*255/16), RNE
    q = fminf(fmaxf(q, 0.0f), 16.0f);
    v = (unsigned char)(int)q;
  }
  bins[idx] = v;
}

// ---------------- K2: mode pool 11x11 -> u8 mode bins [2,3,504,504] ----------------
__global__ __launch_bounds__(256) void k_mode(const unsigned char* __restrict__ bins,
                                              unsigned char* __restrict__ hmode) {
  __shared__ unsigned char tile[26 * 26];
  int bc  = blockIdx.z;
  int ty0 = blockIdx.y * 16, tx0 = blockIdx.x * 16;
  const unsigned char* src = bins + bc * HP * HP;
  for (int i = threadIdx.x; i < 26 * 26; i += 256) {
    int r = i / 26, cl = i % 26;
    int Y = ty0 + r, X = tx0 + cl;
    tile[i] = (Y < HP && X < HP) ? src[Y * HP + X] : (unsigned char)0;
  }
  __syncthreads();
  int ty = threadIdx.x >> 4, tx = threadIdx.x & 15;
  int oy = ty0 + ty, ox = tx0 + tx;
  if (oy >= HM || ox >= HM) return;
  // 17 counters packed 8 bits each into 3x u64 (max count 121 < 256)
  unsigned long long w0 = 0, w1 = 0, w2 = 0;
  for (int dy = 0; dy < 11; dy++) {
    #pragma unroll
    for (int dx = 0; dx < 11; dx++) {
      int b = tile[(ty + dy) * 26 + tx + dx];
      unsigned long long inc = 1ull << ((b & 7) * 8);
      if (b < 8) w0 += inc;
      else if (b < 16) w1 += inc;
      else w2 += inc;
    }
  }
  int best = -1, bestb = 0;
  #pragma unroll
  for (int b = 0; b < 17; b++) {
    int cnt;
    if (b < 8)       cnt = (int)((w0 >> (b * 8)) & 0xff);
    else if (b < 16) cnt = (int)((w1 >> ((b - 8) * 8)) & 0xff);
    else             cnt = (int)(w2 & 0xff);
    if (cnt > best) { best = cnt; bestb = b; }   // strict > keeps lowest bin on tie
  }
  hmode[bc * HM * HM + oy * HM + ox] = (unsigned char)bestb;
}

// ---------------- K3: fused conv1(1x1 3->64)+maxleaky + grouped conv2 + minleaky
// ----------------     + downgrade(3x3 s3 p1 shared)+leaky -> d1 [2,64,168,168]
__global__ __launch_bounds__(256) void k_prepare(const unsigned char* __restrict__ hmode,
                                                 const float* __restrict__ w1,
                                                 const float* __restrict__ b1,
                                                 const float* __restrict__ w2,
                                                 const float* __restrict__ b2,
                                                 const float* __restrict__ down_k,
                                                 const float* __restrict__ down_b,
                                                 float* __restrict__ d1) {
  int bc = blockIdx.y;           // b*64 + c
  int b  = bc >> 6;
  int c  = bc & 63;
  int pix = blockIdx.x * 256 + threadIdx.x;
  if (pix >= 168 * 168) return;
  int oy = pix / 168, ox = pix % 168;
  int c0 = (c >> 1) << 1;
  float w1a0 = w1[c0 * 3], w1a1 = w1[c0 * 3 + 1], w1a2 = w1[c0 * 3 + 2], b1a = b1[c0];
  float w1b0 = w1[(c0 + 1) * 3], w1b1 = w1[(c0 + 1) * 3 + 1], w1b2 = w1[(c0 + 1) * 3 + 2], b1b = b1[c0 + 1];
  float w2a = w2[c * 2], w2b = w2[c * 2 + 1], b2c = b2[c];
  float kb = *down_b;
  const unsigned char* h0p = hmode + (b * 3 + 0) * HM * HM;
  const unsigned char* h1p = hmode + (b * 3 + 1) * HM * HM;
  const unsigned char* h2p = hmode + (b * 3 + 2) * HM * HM;
  float acc = 0.0f;
  #pragma unroll
  for (int ky = 0; ky < 3; ky++) {
    int y = 3 * oy - 1 + ky;
    if (y < 0 || y >= HM) continue;
    #pragma unroll
    for (int kx = 0; kx < 3; kx++) {
      int xx = 3 * ox - 1 + kx;
      if (xx < 0 || xx >= HM) continue;
      int o = y * HM + xx;
      float hh0 = h0p[o] * (1.0f / 16.0f);
      float hh1 = h1p[o] * (1.0f / 16.0f);
      float hh2 = h2p[o] * (1.0f / 16.0f);
      float a0 = w1a0 * hh0 + w1a1 * hh1 + w1a2 * hh2 + b1a;
      float a1 = w1b0 * hh0 + w1b1 * hh1 + w1b2 * hh2 + b1b;
      a0 = (a0 <= 0.1f) ? a0 : 0.1f + 0.01f * (a0 - 0.1f);   // max_leaky
      a1 = (a1 <= 0.1f) ? a1 : 0.1f + 0.01f * (a1 - 0.1f);
      float v = w2a * a0 + w2b * a1 + b2c;
      v = (v >= 0.1f) ? v : 0.1f + 0.01f * (v - 0.1f);       // min_leaky
      acc += down_k[ky * 3 + kx] * v;
    }
  }
  float r = acc + kb;
  r = (r >= 0.0f) ? r : 0.01f * r;
  d1[bc * 168 * 168 + pix] = r;
}

// ---------------- K4: generic downgrade (3x3 s3 p1 shared) + leaky ----------------
__global__ __launch_bounds__(256) void k_down(const float* __restrict__ din,
                                              float* __restrict__ dout,
                                              const float* __restrict__ down_k,
                                              const float* __restrict__ down_b,
                                              int S, int So) {
  int bc = blockIdx.y;
  int pix = blockIdx.x * 256 + threadIdx.x;
  if (pix >= So * So) return;
  int oy = pix / So, ox = pix % So;
  const float* p = din + bc * S * S;
  float acc = 0.0f;
  #pragma unroll
  for (int ky = 0; ky < 3; ky++) {
    int y = 3 * oy - 1 + ky;
    if (y < 0 || y >= S) continue;
    #pragma unroll
    for (int kx = 0; kx < 3; kx++) {
      int xx = 3 * ox - 1 + kx;
      if (xx < 0 || xx >= S) continue;
      acc += down_k[ky * 3 + kx] * p[y * S + xx];
    }
  }
  float r = acc + *down_b;
  r = (r >= 0.0f) ? r : 0.01f * r;
  dout[bc * So * So + pix] = r;
}

// ---------------- K5: fused 5-level resize + 5x5 shared conv + BN + leaky + sum ----------------
// block: 256 threads, 64x64 output tile per (b,c); LDS holds 68x68 upsampled z.
__global__ __launch_bounds__(256) void k_score(const float* __restrict__ d1,
                                               const float* __restrict__ d2,
                                               const float* __restrict__ d3,
                                               const float* __restrict__ d4,
                                               const float* __restrict__ d5,
                                               const float* __restrict__ interp_k,
                                               const float* __restrict__ interp_b,
                                               const float* __restrict__ i_gamma,
                                               const float* __restrict__ i_beta,
                                               const float* __restrict__ i_mean,
                                               const float* __restrict__ i_var,
                                               float* __restrict__ score) {
  __shared__ float z[68 * 68];
  int bc = blockIdx.y;
  int c  = bc & 63;
  int tile = blockIdx.x;                    // 0..63
  int ty0 = (tile >> 3) * 64, tx0 = (tile & 7) * 64;
  float K[25];
  #pragma unroll
  for (int i = 0; i < 25; i++) K[i] = interp_k[i];
  float ib  = *interp_b;
  float isc = i_gamma[c] * rsqrtf(i_var[c] + 1e-5f);
  float ibe = i_beta[c] - i_mean[c] * isc;          // (v-mean)*isc+beta = v*isc+ibe
  int tid = threadIdx.x;
  int oyl = (tid >> 4) << 2, oxl = (tid & 15) << 2; // 4x4 px per thread
  float acc[4][4];
  #pragma unroll
  for (int i = 0; i < 4; i++)
    #pragma unroll
    for (int j = 0; j < 4; j++) acc[i][j] = 0.0f;

  const float* dls[5] = {d1, d2, d3, d4, d5};
  const int Ls[5] = {168, 56, 19, 7, 3};

  #pragma unroll
  for (int lvl = 0; lvl < 5; lvl++) {
    const int L = Ls[lvl];
    const float* dp = dls[lvl] + bc * L * L;
    const float scaleL = (float)L / 512.0f;         // exact dyadic
    __syncthreads();
    // stage bilinear-upsampled z (zero outside image: conv pad=2 is zero-pad)
    for (int i = tid; i < 68 * 68; i += 256) {
      int r = i / 68, cl = i % 68;
      int Y = ty0 - 2 + r, X = tx0 - 2 + cl;
      float v = 0.0f;
      if (Y >= 0 && Y < 512 && X >= 0 && X < 512) {
        float fy = (Y + 0.5f) * scaleL - 0.5f;
        fy = fminf(fmaxf(fy, 0.0f), (float)(L - 1));
        int y0 = (int)fy; float fyr = fy - y0; int y1 = min(y0 + 1, L - 1);
        float fx = (X + 0.5f) * scaleL - 0.5f;
        fx = fminf(fmaxf(fx, 0.0f), (float)(L - 1));
        int x0 = (int)fx; float fxr = fx - x0; int x1 = min(x0 + 1, L - 1);
        float v00 = dp[y0 * L + x0], v01 = dp[y0 * L + x1];
        float v10 = dp[y1 * L + x0], v11 = dp[y1 * L + x1];
        v = (1.0f - fyr) * ((1.0f - fxr) * v00 + fxr * v01) +
            fyr * ((1.0f - fxr) * v10 + fxr * v11);
      }
      z[i] = v;
    }
    __syncthreads();
    float tmp[4][4];
    #pragma unroll
    for (int i = 0; i < 4; i++)
      #pragma unroll
      for (int j = 0; j < 4; j++) tmp[i][j] = 0.0f;
    #pragma unroll
    for (int iy = 0; iy < 8; iy++) {
      float zr[8];
      #pragma unroll
      for (int j = 0; j < 8; j++) zr[j] = z[(oyl + iy) * 68 + oxl + j];
      #pragma unroll
      for (int ky = 0; ky < 5; ky++) {
        const int o = iy - ky;
        if (o >= 0 && o < 4) {
          #pragma unroll
          for (int ox = 0; ox < 4; ox++)
            #pragma unroll
            for (int kx = 0; kx < 5; kx++)
              tmp[o][ox] += K[ky * 5 + kx] * zr[ox + kx];
        }
      }
    }
    #pragma unroll
    for (int i = 0; i < 4; i++)
      #pragma unroll
      for (int j = 0; j < 4; j++) {
        float v = (tmp[i][j] + ib) * isc + ibe;
        v = (v >= 0.0f) ? v : 0.01f * v;
        acc[i][j] += v;
      }
  }
  float* op = score + bc * 512 * 512;
  #pragma unroll
  for (int i = 0; i < 4; i++) {
    int Y = ty0 + oyl + i;
    float4 vv = make_float4(acc[i][0], acc[i][1], acc[i][2], acc[i][3]);
    *(float4*)(op + Y * 512 + tx0 + oxl) = vv;
  }
}

// ---------------- K6: ft horizontal pass: Bs = hsum11(affine(score)) ----------------
__global__ __launch_bounds__(256) void k_ft_h(const float* __restrict__ score,
                                              float* __restrict__ Bs,
                                              const float* __restrict__ ft_gamma,
                                              const float* __restrict__ ft_beta,
                                              const float* __restrict__ ft_mean,
                                              const float* __restrict__ ft_var,
                                              const float* __restrict__ ft_k,
                                              const float* __restrict__ ft_b) {
  int idx = blockIdx.x * 256 + threadIdx.x;     // exactly NB*C2*512*512 threads
  int x = idx & 511;
  int t = idx >> 9;        // bc*512 + y
  int bc = t >> 9;
  int c = bc & 63;
  float sc = ft_gamma[c] * rsqrtf(ft_var[c] + 1e-5f);
  float fk = *ft_k, fb = *ft_b;
  float A  = sc * fk;
  float Cc = (ft_beta[c] - ft_mean[c] * sc) * fk + fb;
  const float* row = score + ((long long)t << 9);
  float sum = 0.0f;
  #pragma unroll
  for (int dx = -5; dx <= 5; dx++) {
    int xx = x + dx;
    if (xx >= 0 && xx < 512) sum += row[xx] * A + Cc;   // zero-pad applies to s
  }
  Bs[idx] = sum;
}

// ---------------- K7: ft vertical pass + emphase, in place on score ----------------
__global__ __launch_bounds__(256) void k_ft_v(float* __restrict__ score,
                                              const float* __restrict__ Bs,
                                              const float* __restrict__ ft_gamma,
                                              const float* __restrict__ ft_beta,
                                              const float* __restrict__ ft_mean,
                                              const float* __restrict__ ft_var,
                                              const float* __restrict__ ft_k,
                                              const float* __restrict__ ft_b,
                                              const float* __restrict__ emph_w) {
  int idx = blockIdx.x * 256 + threadIdx.x;
  int x = idx & 511;
  int t = idx >> 9;
  int y = t & 511;
  int bc = t >> 9;
  int c = bc & 63;
  float sc = ft_gamma[c] * rsqrtf(ft_var[c] + 1e-5f);
  float fk = *ft_k, fb = *ft_b;
  float A  = sc * fk;
  float Cc = (ft_beta[c] - ft_mean[c] * sc) * fk + fb;
  float s_center = score[idx] * A + Cc;
  float vsum = 0.0f;
  const float* Bp = Bs + ((long long)bc << 18);
  #pragma unroll
  for (int dy = -5; dy <= 5; dy++) {
    int yy = y + dy;
    if (yy >= 0 && yy < 512) vsum += Bp[(yy << 9) + x];
  }
  float avg = vsum * (1.0f / 121.0f);
  float w = emph_w[c];
  score[idx] = s_center + w * (s_center - avg);
}

extern "C" void kernel_launch(void* const* d_in, const int* in_sizes, int n_in,
                              void* d_out, int out_size, void* d_ws, size_t ws_size,
                              hipStream_t stream) {
  const float* x        = (const float*)d_in[0];
  const float* w1       = (const float*)d_in[1];
  const float* b1       = (const float*)d_in[2];
  const float* w2       = (const float*)d_in[3];
  const float* b2       = (const float*)d_in[4];
  const float* down_k   = (const float*)d_in[5];
  const float* down_b   = (const float*)d_in[6];
  const float* ft_gamma = (const float*)d_in[7];
  const float* ft_beta  = (const float*)d_in[8];
  const float* ft_mean  = (const float*)d_in[9];
  const float* ft_var   = (const float*)d_in[10];
  const float* ft_k     = (const float*)d_in[11];
  const float* ft_b     = (const float*)d_in[12];
  const float* emph_w   = (const float*)d_in[13];
  const float* interp_k = (const float*)d_in[14];
  const float* interp_b = (const float*)d_in[15];
  const float* i_gamma  = (const float*)d_in[16];
  const float* i_beta   = (const float*)d_in[17];
  const float* i_mean   = (const float*)d_in[18];
  const float* i_var    = (const float*)d_in[19];
  float* score = (float*)d_out;                  // [2,64,512,512]

  char* ws = (char*)d_ws;
  size_t off = 0;
  auto alloc = [&](size_t bytes) { size_t r = off; off += (bytes + 255) & ~(size_t)255; return r; };
  unsigned char* bins  = (unsigned char*)(ws + alloc((size_t)NB * CIN * HP * HP));
  unsigned char* hmode = (unsigned char*)(ws + alloc((size_t)NB * CIN * HM * HM));
  float* d1 = (float*)(ws + alloc((size_t)NB * C2 * 168 * 168 * 4));
  float* d2 = (float*)(ws + alloc((size_t)NB * C2 * 56 * 56 * 4));
  float* d3 = (float*)(ws + alloc((size_t)NB * C2 * 19 * 19 * 4));
  float* d4 = (float*)(ws + alloc((size_t)NB * C2 * 7 * 7 * 4));
  float* d5 = (float*)(ws + alloc((size_t)NB * C2 * 3 * 3 * 4));
  float* Bs = (float*)(ws + alloc((size_t)NB * C2 * 512 * 512 * 4));

  // 1. quantize + pad
  {
    int total = NB * CIN * HP * HP;
    k_quant<<<(total + 255) / 256, 256, 0, stream>>>(x, bins);
  }
  // 2. mode pool
  k_mode<<<dim3(32, 32, NB * CIN), 256, 0, stream>>>(bins, hmode);
  // 3. fused convs + first downgrade -> d1 (168)
  k_prepare<<<dim3((168 * 168 + 255) / 256, NB * C2), 256, 0, stream>>>(
      hmode, w1, b1, w2, b2, down_k, down_b, d1);
  // 4. downgrade chain
  k_down<<<dim3((56 * 56 + 255) / 256, NB * C2), 256, 0, stream>>>(d1, d2, down_k, down_b, 168, 56);
  k_down<<<dim3((19 * 19 + 255) / 256, NB * C2), 256, 0, stream>>>(d2, d3, down_k, down_b, 56, 19);
  k_down<<<dim3((7 * 7 + 255) / 256, NB * C2), 256, 0, stream>>>(d3, d4, down_k, down_b, 19, 7);
  k_down<<<dim3((3 * 3 + 255) / 256, NB * C2), 256, 0, stream>>>(d4, d5, down_k, down_b, 7, 3);
  // 5. fused 5-level score accumulation -> d_out
  k_score<<<dim3(64, NB * C2), 256, 0, stream>>>(d1, d2, d3, d4, d5, interp_k, interp_b,
                                                 i_gamma, i_beta, i_mean, i_var, score);
  // 6. ft x3 (BN + 1x1 shared conv folded to affine; emphase via separable box sum)
  int nblk = (NB * C2 * 512 * 512) / 256;
  for (int it = 0; it < 3; it++) {
    k_ft_h<<<nblk, 256, 0, stream>>>(score, Bs, ft_gamma, ft_beta, ft_mean, ft_var, ft_k, ft_b);
    k_ft_v<<<nblk, 256, 0, stream>>>(score, Bs, ft_gamma, ft_beta, ft_mean, ft_var, ft_k, ft_b, emph_w);
  }
}

// Round 2
// 2181.568 us; speedup vs baseline: 1.1509x; 1.1509x over previous
//
#include <hip/hip_runtime.h>

#define NB 2
#define CIN 3
#define HH 512
#define WW 512
#define C2 64
#define HP 514   // padded input for mode pool
#define HM 504   // mode-pool output size

// ---------------- K1: quantize + pad -> u8 bins [2,3,514,514] ----------------
__global__ __launch_bounds__(256) void k_quant(const float* __restrict__ x,
                                               unsigned char* __restrict__ bins) {
  int idx = blockIdx.x * 256 + threadIdx.x;
  const int total = NB * CIN * HP * HP;
  if (idx >= total) return;
  int xp = idx % HP;
  int t  = idx / HP;
  int yp = t % HP;
  int bc = t / HP;
  unsigned char v = 0;
  if (xp >= 1 && xp <= WW && yp >= 1 && yp <= HH) {
    float val = x[(bc * HH + (yp - 1)) * WW + (xp - 1)];
    float q = rintf((val * 255.0f) / 16.0f);   // matches jnp.round(x*255/16), RNE
    q = fminf(fmaxf(q, 0.0f), 16.0f);
    v = (unsigned char)(int)q;
  }
  bins[idx] = v;
}

// ---------------- K2: mode pool 11x11 -> u8 mode bins [2,3,504,504] ----------------
__global__ __launch_bounds__(256) void k_mode(const unsigned char* __restrict__ bins,
                                              unsigned char* __restrict__ hmode) {
  __shared__ unsigned char tile[26 * 26];
  int bc  = blockIdx.z;
  int ty0 = blockIdx.y * 16, tx0 = blockIdx.x * 16;
  const unsigned char* src = bins + bc * HP * HP;
  for (int i = threadIdx.x; i < 26 * 26; i += 256) {
    int r = i / 26, cl = i % 26;
    int Y = ty0 + r, X = tx0 + cl;
    tile[i] = (Y < HP && X < HP) ? src[Y * HP + X] : (unsigned char)0;
  }
  __syncthreads();
  int ty = threadIdx.x >> 4, tx = threadIdx.x & 15;
  int oy = ty0 + ty, ox = tx0 + tx;
  if (oy >= HM || ox >= HM) return;
  unsigned long long w0 = 0, w1 = 0, w2 = 0;
  for (int dy = 0; dy < 11; dy++) {
    #pragma unroll
    for (int dx = 0; dx < 11; dx++) {
      int b = tile[(ty + dy) * 26 + tx + dx];
      unsigned long long inc = 1ull << ((b & 7) * 8);
      if (b < 8) w0 += inc;
      else if (b < 16) w1 += inc;
      else w2 += inc;
    }
  }
  int best = -1, bestb = 0;
  #pragma unroll
  for (int b = 0; b < 17; b++) {
    int cnt;
    if (b < 8)       cnt = (int)((w0 >> (b * 8)) & 0xff);
    else if (b < 16) cnt = (int)((w1 >> ((b - 8) * 8)) & 0xff);
    else             cnt = (int)(w2 & 0xff);
    if (cnt > best) { best = cnt; bestb = b; }   // strict > keeps lowest bin on tie
  }
  hmode[bc * HM * HM + oy * HM + ox] = (unsigned char)bestb;
}

// ---------------- K3: fused conv1+maxleaky + grouped conv2 + minleaky + downgrade ----------------
__global__ __launch_bounds__(256) void k_prepare(const unsigned char* __restrict__ hmode,
                                                 const float* __restrict__ w1,
                                                 const float* __restrict__ b1,
                                                 const float* __restrict__ w2,
                                                 const float* __restrict__ b2,
                                                 const float* __restrict__ down_k,
                                                 const float* __restrict__ down_b,
                                                 float* __restrict__ d1) {
  int bc = blockIdx.y;
  int b  = bc >> 6;
  int c  = bc & 63;
  int pix = blockIdx.x * 256 + threadIdx.x;
  if (pix >= 168 * 168) return;
  int oy = pix / 168, ox = pix % 168;
  int c0 = (c >> 1) << 1;
  float w1a0 = w1[c0 * 3], w1a1 = w1[c0 * 3 + 1], w1a2 = w1[c0 * 3 + 2], b1a = b1[c0];
  float w1b0 = w1[(c0 + 1) * 3], w1b1 = w1[(c0 + 1) * 3 + 1], w1b2 = w1[(c0 + 1) * 3 + 2], b1b = b1[c0 + 1];
  float w2a = w2[c * 2], w2b = w2[c * 2 + 1], b2c = b2[c];
  float kb = *down_b;
  const unsigned char* h0p = hmode + (b * 3 + 0) * HM * HM;
  const unsigned char* h1p = hmode + (b * 3 + 1) * HM * HM;
  const unsigned char* h2p = hmode + (b * 3 + 2) * HM * HM;
  float acc = 0.0f;
  #pragma unroll
  for (int ky = 0; ky < 3; ky++) {
    int y = 3 * oy - 1 + ky;
    if (y < 0 || y >= HM) continue;
    #pragma unroll
    for (int kx = 0; kx < 3; kx++) {
      int xx = 3 * ox - 1 + kx;
      if (xx < 0 || xx >= HM) continue;
      int o = y * HM + xx;
      float hh0 = h0p[o] * (1.0f / 16.0f);
      float hh1 = h1p[o] * (1.0f / 16.0f);
      float hh2 = h2p[o] * (1.0f / 16.0f);
      float a0 = w1a0 * hh0 + w1a1 * hh1 + w1a2 * hh2 + b1a;
      float a1 = w1b0 * hh0 + w1b1 * hh1 + w1b2 * hh2 + b1b;
      a0 = (a0 <= 0.1f) ? a0 : 0.1f + 0.01f * (a0 - 0.1f);
      a1 = (a1 <= 0.1f) ? a1 : 0.1f + 0.01f * (a1 - 0.1f);
      float v = w2a * a0 + w2b * a1 + b2c;
      v = (v >= 0.1f) ? v : 0.1f + 0.01f * (v - 0.1f);
      acc += down_k[ky * 3 + kx] * v;
    }
  }
  float r = acc + kb;
  r = (r >= 0.0f) ? r : 0.01f * r;
  d1[bc * 168 * 168 + pix] = r;
}

// ---------------- K4: generic downgrade (3x3 s3 p1 shared) + leaky ----------------
__global__ __launch_bounds__(256) void k_down(const float* __restrict__ din,
                                              float* __restrict__ dout,
                                              const float* __restrict__ down_k,
                                              const float* __restrict__ down_b,
                                              int S, int So) {
  int bc = blockIdx.y;
  int pix = blockIdx.x * 256 + threadIdx.x;
  if (pix >= So * So) return;
  int oy = pix / So, ox = pix % So;
  const float* p = din + bc * S * S;
  float acc = 0.0f;
  #pragma unroll
  for (int ky = 0; ky < 3; ky++) {
    int y = 3 * oy - 1 + ky;
    if (y < 0 || y >= S) continue;
    #pragma unroll
    for (int kx = 0; kx < 3; kx++) {
      int xx = 3 * ox - 1 + kx;
      if (xx < 0 || xx >= S) continue;
      acc += down_k[ky * 3 + kx] * p[y * S + xx];
    }
  }
  float r = acc + *down_b;
  r = (r >= 0.0f) ? r : 0.01f * r;
  dout[bc * So * So + pix] = r;
}

// ---------------- K_lut: bilinear LUT per level per coordinate ----------------
__global__ __launch_bounds__(256) void k_lut(int2* __restrict__ lut_i,
                                             float* __restrict__ lut_w) {
  int idx = blockIdx.x * 256 + threadIdx.x;   // 5*512
  if (idx >= 5 * 512) return;
  int lvl = idx >> 9, Y = idx & 511;
  const int Ls[5] = {168, 56, 19, 7, 3};
  int L = Ls[lvl];
  float f = (Y + 0.5f) * ((float)L / 512.0f) - 0.5f;
  f = fminf(fmaxf(f, 0.0f), (float)(L - 1));
  int y0 = (int)f;
  float w = f - (float)y0;
  int y1 = min(y0 + 1, L - 1);
  lut_i[idx] = make_int2(y0, y1);
  lut_w[idx] = w;
}

// ---------------- K5: fused 5-level resize + 5x5 shared conv + BN + leaky + sum ----------------
__global__ __launch_bounds__(256, 4) void k_score(const float* __restrict__ d1,
                                                  const float* __restrict__ d2,
                                                  const float* __restrict__ d3,
                                                  const float* __restrict__ d4,
                                                  const float* __restrict__ d5,
                                                  const int2* __restrict__ lut_i,
                                                  const float* __restrict__ lut_w,
                                                  const float* __restrict__ interp_k,
                                                  const float* __restrict__ interp_b,
                                                  const float* __restrict__ i_gamma,
                                                  const float* __restrict__ i_beta,
                                                  const float* __restrict__ i_mean,
                                                  const float* __restrict__ i_var,
                                                  float* __restrict__ score) {
  __shared__ float z[68 * 68];
  int bc = blockIdx.y;
  int c  = bc & 63;
  int tile = blockIdx.x;                    // 0..63
  int tyi = tile >> 3, txi = tile & 7;
  int ty0 = tyi * 64, tx0 = txi * 64;
  bool interior = (tyi >= 1 && tyi <= 6 && txi >= 1 && txi <= 6);
  // conv taps into SGPRs (uniform) to keep VGPR count low
  float K[25];
  #pragma unroll
  for (int i = 0; i < 25; i++)
    K[i] = __int_as_float(__builtin_amdgcn_readfirstlane(__float_as_int(interp_k[i])));
  float ib  = __int_as_float(__builtin_amdgcn_readfirstlane(__float_as_int(*interp_b)));
  float isc = i_gamma[c] * rsqrtf(i_var[c] + 1e-5f);
  float ibe = i_beta[c] - i_mean[c] * isc;
  int tid = threadIdx.x;
  int oyl = (tid >> 4) << 2, oxl = (tid & 15) << 2; // 4x4 px per thread
  float acc[4][4];
  #pragma unroll
  for (int i = 0; i < 4; i++)
    #pragma unroll
    for (int j = 0; j < 4; j++) acc[i][j] = 0.0f;

  const float* dls[5] = {d1, d2, d3, d4, d5};
  const int Ls[5] = {168, 56, 19, 7, 3};

  #pragma unroll
  for (int lvl = 0; lvl < 5; lvl++) {
    const int L = Ls[lvl];
    const float* dp = dls[lvl] + bc * L * L;
    const int2*  li = lut_i + lvl * 512;
    const float* lw = lut_w + lvl * 512;
    __syncthreads();
    if (interior) {
      for (int i = tid; i < 68 * 68; i += 256) {
        int r = i / 68, cl = i - r * 68;
        int Y = ty0 - 2 + r, X = tx0 - 2 + cl;
        int2 iy = li[Y]; float wy = lw[Y];
        int2 ix = li[X]; float wx = lw[X];
        const float* r0p = dp + iy.x * L;
        const float* r1p = dp + iy.y * L;
        float v00 = r0p[ix.x], v01 = r0p[ix.y];
        float v10 = r1p[ix.x], v11 = r1p[ix.y];
        float top = v00 + wx * (v01 - v00);
        float bot = v10 + wx * (v11 - v10);
        z[i] = top + wy * (bot - top);
      }
    } else {
      for (int i = tid; i < 68 * 68; i += 256) {
        int r = i / 68, cl = i - r * 68;
        int Y = ty0 - 2 + r, X = tx0 - 2 + cl;
        float v = 0.0f;
        if (Y >= 0 && Y < 512 && X >= 0 && X < 512) {
          int2 iy = li[Y]; float wy = lw[Y];
          int2 ix = li[X]; float wx = lw[X];
          const float* r0p = dp + iy.x * L;
          const float* r1p = dp + iy.y * L;
          float v00 = r0p[ix.x], v01 = r0p[ix.y];
          float v10 = r1p[ix.x], v11 = r1p[ix.y];
          float top = v00 + wx * (v01 - v00);
          float bot = v10 + wx * (v11 - v10);
          v = top + wy * (bot - top);
        }
        z[i] = v;
      }
    }
    __syncthreads();
    float tmp[4][4];
    #pragma unroll
    for (int i = 0; i < 4; i++)
      #pragma unroll
      for (int j = 0; j < 4; j++) tmp[i][j] = 0.0f;
    #pragma unroll
    for (int iy = 0; iy < 8; iy++) {
      const float4 za = *(const float4*)&z[(oyl + iy) * 68 + oxl];
      const float4 zb = *(const float4*)&z[(oyl + iy) * 68 + oxl + 4];
      float zr[8] = {za.x, za.y, za.z, za.w, zb.x, zb.y, zb.z, zb.w};
      #pragma unroll
      for (int ky = 0; ky < 5; ky++) {
        const int o = iy - ky;
        if (o >= 0 && o < 4) {
          #pragma unroll
          for (int ox = 0; ox < 4; ox++)
            #pragma unroll
            for (int kx = 0; kx < 5; kx++)
              tmp[o][ox] += K[ky * 5 + kx] * zr[ox + kx];
        }
      }
    }
    #pragma unroll
    for (int i = 0; i < 4; i++)
      #pragma unroll
      for (int j = 0; j < 4; j++) {
        float v = (tmp[i][j] + ib) * isc + ibe;
        v = (v >= 0.0f) ? v : 0.01f * v;
        acc[i][j] += v;
      }
  }
  float* op = score + bc * 512 * 512;
  #pragma unroll
  for (int i = 0; i < 4; i++) {
    int Y = ty0 + oyl + i;
    float4 vv = make_float4(acc[i][0], acc[i][1], acc[i][2], acc[i][3]);
    *(float4*)(op + Y * 512 + tx0 + oxl) = vv;
  }
}

// ---------------- K6: fused 3x ft (affine + 11x11 box emphase), LDS-tiled ----------------
// Tile: 64 rows x 32 cols output, halo 15 -> staged 94x62. A: s values; B: row sums.
#define FT_SA 63
#define FT_BW 53

template <int K>
__device__ __forceinline__ void ft_iter(float* Asm, float* Bsm, float w, float Aff, float Cc,
                                        int gy0, int gx0, float* out_g, int tid) {
  // --- hsum: B[r][c-5(K+1)] = sum_{dc=-5..5} A[r][c+dc]
  // rows [5K, 94-5K), output cols [5(K+1), 62-5(K+1))
  const int R0 = 5 * K;
  const int Rh = 94 - 10 * K;
  const int Ch = 52 - 10 * K;
  const int Cq = (Ch + 3) / 4;
  const int C0 = 5 * K + 5;
  for (int idx = tid; idx < Rh * Cq; idx += 256) {
    int r = idx / Cq, q = idx - r * Cq;
    int rr = R0 + r;
    int c0 = C0 + 4 * q;
    const float* ap = Asm + rr * FT_SA + (c0 - 5);
    float wv[14];
    #pragma unroll
    for (int j = 0; j < 14; j++) wv[j] = ap[j];
    float s0 = 0.0f;
    #pragma unroll
    for (int j = 0; j < 11; j++) s0 += wv[j];
    float s1 = s0 - wv[0] + wv[11];
    float s2 = s1 - wv[1] + wv[12];
    float s3 = s2 - wv[2] + wv[13];
    float* bp = Bsm + rr * FT_BW + 4 * q;
    int rem = Ch - 4 * q;
    bp[0] = s0;
    if (rem > 1) bp[1] = s1;
    if (rem > 2) bp[2] = s2;
    if (rem > 3) bp[3] = s3;
  }
  __syncthreads();
  // --- vsum + emphase update on region K+1: rows [5(K+1), 94-5(K+1)), cols same
  const int Rv = 84 - 10 * K;
  const int Cv = Ch;
  const int Rq = (Rv + 3) / 4;
  for (int idx = tid; idx < Rq * Cv; idx += 256) {
    int rq = idx / Cv, cb = idx - rq * Cv;
    int r0 = C0 + 4 * rq;
    const float* bp = Bsm + (r0 - 5) * FT_BW + cb;
    float bv[14];
    #pragma unroll
    for (int j = 0; j < 14; j++) bv[j] = bp[j * FT_BW];
    float v0 = 0.0f;
    #pragma unroll
    for (int j = 0; j < 11; j++) v0 += bv[j];
    float v1 = v0 - bv[0] + bv[11];
    float v2 = v1 - bv[1] + bv[12];
    float v3 = v2 - bv[2] + bv[13];
    float vs[4] = {v0, v1, v2, v3};
    int rem = Rv - 4 * rq;
    int cc = C0 + cb;
    #pragma unroll
    for (int j = 0; j < 4; j++) {
      if (j < rem) {
        int rr = r0 + j;
        float s_c = Asm[rr * FT_SA + cc];
        float avg = vs[j] * (1.0f / 121.0f);
        float o = s_c + w * (s_c - avg);
        if (K < 2) {
          int gy = gy0 - 15 + rr, gx = gx0 - 15 + cc;
          bool in = (gy >= 0 && gy < 512 && gx >= 0 && gx < 512);
          Asm[rr * FT_SA + cc] = in ? (Aff * o + Cc) : 0.0f;
        } else {
          // K==2: region is exactly the 64x32 core (rows/cols [15, ...)), always in-image
          out_g[(gy0 - 15 + rr) * 512 + (gx0 - 15 + cc)] = o;
        }
      }
    }
  }
  __syncthreads();
}

__global__ __launch_bounds__(256) void k_ft(const float* __restrict__ s_in,
                                            float* __restrict__ s_out,
                                            const float* __restrict__ ft_gamma,
                                            const float* __restrict__ ft_beta,
                                            const float* __restrict__ ft_mean,
                                            const float* __restrict__ ft_var,
                                            const float* __restrict__ ft_k,
                                            const float* __restrict__ ft_b,
                                            const float* __restrict__ emph_w) {
  __shared__ float Asm[94 * FT_SA];
  __shared__ float Bsm[94 * FT_BW];
  int bc = blockIdx.y;
  int c  = bc & 63;
  int tile = blockIdx.x;                 // 16 x-tiles * 8 y-tiles
  int gx0 = (tile & 15) * 32;
  int gy0 = (tile >> 4) * 64;
  float sc = ft_gamma[c] * rsqrtf(ft_var[c] + 1e-5f);
  float fk = *ft_k, fb = *ft_b;
  float Aff = sc * fk;
  float Cc  = (ft_beta[c] - ft_mean[c] * sc) * fk + fb;
  float w   = emph_w[c];
  const float* sp = s_in + ((long long)bc << 18);
  float* op = s_out + ((long long)bc << 18);
  int tid = threadIdx.x;
  // stage s1 = Aff*score + Cc (0 outside image)
  for (int i = tid; i < 94 * 62; i += 256) {
    int r = i / 62, cl = i - r * 62;
    int gy = gy0 - 15 + r, gx = gx0 - 15 + cl;
    float v = 0.0f;
    if (gy >= 0 && gy < 512 && gx >= 0 && gx < 512)
      v = Aff * sp[(gy << 9) + gx] + Cc;
    Asm[r * FT_SA + cl] = v;
  }
  __syncthreads();
  ft_iter<0>(Asm, Bsm, w, Aff, Cc, gy0, gx0, op, tid);
  ft_iter<1>(Asm, Bsm, w, Aff, Cc, gy0, gx0, op, tid);
  ft_iter<2>(Asm, Bsm, w, Aff, Cc, gy0, gx0, op, tid);
}

extern "C" void kernel_launch(void* const* d_in, const int* in_sizes, int n_in,
                              void* d_out, int out_size, void* d_ws, size_t ws_size,
                              hipStream_t stream) {
  const float* x        = (const float*)d_in[0];
  const float* w1       = (const float*)d_in[1];
  const float* b1       = (const float*)d_in[2];
  const float* w2       = (const float*)d_in[3];
  const float* b2       = (const float*)d_in[4];
  const float* down_k   = (const float*)d_in[5];
  const float* down_b   = (const float*)d_in[6];
  const float* ft_gamma = (const float*)d_in[7];
  const float* ft_beta  = (const float*)d_in[8];
  const float* ft_mean  = (const float*)d_in[9];
  const float* ft_var   = (const float*)d_in[10];
  const float* ft_k     = (const float*)d_in[11];
  const float* ft_b     = (const float*)d_in[12];
  const float* emph_w   = (const float*)d_in[13];
  const float* interp_k = (const float*)d_in[14];
  const float* interp_b = (const float*)d_in[15];
  const float* i_gamma  = (const float*)d_in[16];
  const float* i_beta   = (const float*)d_in[17];
  const float* i_mean   = (const float*)d_in[18];
  const float* i_var    = (const float*)d_in[19];
  float* out = (float*)d_out;                    // [2,64,512,512]

  char* ws = (char*)d_ws;
  size_t off = 0;
  auto alloc = [&](size_t bytes) { size_t r = off; off += (bytes + 255) & ~(size_t)255; return r; };
  unsigned char* bins  = (unsigned char*)(ws + alloc((size_t)NB * CIN * HP * HP));
  unsigned char* hmode = (unsigned char*)(ws + alloc((size_t)NB * CIN * HM * HM));
  float* d1 = (float*)(ws + alloc((size_t)NB * C2 * 168 * 168 * 4));
  float* d2 = (float*)(ws + alloc((size_t)NB * C2 * 56 * 56 * 4));
  float* d3 = (float*)(ws + alloc((size_t)NB * C2 * 19 * 19 * 4));
  float* d4 = (float*)(ws + alloc((size_t)NB * C2 * 7 * 7 * 4));
  float* d5 = (float*)(ws + alloc((size_t)NB * C2 * 3 * 3 * 4));
  float* s0 = (float*)(ws + alloc((size_t)NB * C2 * 512 * 512 * 4));  // pre-ft score
  int2*  lut_i = (int2*)(ws + alloc((size_t)5 * 512 * 8));
  float* lut_w = (float*)(ws + alloc((size_t)5 * 512 * 4));

  // 1. quantize + pad
  {
    int total = NB * CIN * HP * HP;
    k_quant<<<(total + 255) / 256, 256, 0, stream>>>(x, bins);
  }
  // 2. mode pool
  k_mode<<<dim3(32, 32, NB * CIN), 256, 0, stream>>>(bins, hmode);
  // 2b. bilinear LUTs
  k_lut<<<10, 256, 0, stream>>>(lut_i, lut_w);
  // 3. fused convs + first downgrade -> d1 (168)
  k_prepare<<<dim3((168 * 168 + 255) / 256, NB * C2), 256, 0, stream>>>(
      hmode, w1, b1, w2, b2, down_k, down_b, d1);
  // 4. downgrade chain
  k_down<<<dim3((56 * 56 + 255) / 256, NB * C2), 256, 0, stream>>>(d1, d2, down_k, down_b, 168, 56);
  k_down<<<dim3((19 * 19 + 255) / 256, NB * C2), 256, 0, stream>>>(d2, d3, down_k, down_b, 56, 19);
  k_down<<<dim3((7 * 7 + 255) / 256, NB * C2), 256, 0, stream>>>(d3, d4, down_k, down_b, 19, 7);
  k_down<<<dim3((3 * 3 + 255) / 256, NB * C2), 256, 0, stream>>>(d4, d5, down_k, down_b, 7, 3);
  // 5. fused 5-level score accumulation -> s0 (ws)
  k_score<<<dim3(64, NB * C2), 256, 0, stream>>>(d1, d2, d3, d4, d5, lut_i, lut_w,
                                                 interp_k, interp_b,
                                                 i_gamma, i_beta, i_mean, i_var, s0);
  // 6. fused 3x ft: s0 -> d_out (one dispatch, all iterations in LDS)
  k_ft<<<dim3(128, NB * C2), 256, 0, stream>>>(s0, out, ft_gamma, ft_beta, ft_mean,
                                               ft_var, ft_k, ft_b, emph_w);
}

// Round 3
// 894.392 us; speedup vs baseline: 2.8071x; 2.4392x over previous
//
#include <hip/hip_runtime.h>

#define NB 2
#define CIN 3
#define HH 512
#define WW 512
#define C2 64
#define HP 514   // padded input for mode pool
#define HM 504   // mode-pool output size

// ---------------- K1: quantize + pad -> u8 bins [2,3,514,514] ----------------
__global__ __launch_bounds__(256) void k_quant(const float* __restrict__ x,
                                               unsigned char* __restrict__ bins) {
  int idx = blockIdx.x * 256 + threadIdx.x;
  const int total = NB * CIN * HP * HP;
  if (idx >= total) return;
  int xp = idx % HP;
  int t  = idx / HP;
  int yp = t % HP;
  int bc = t / HP;
  unsigned char v = 0;
  if (xp >= 1 && xp <= WW && yp >= 1 && yp <= HH) {
    float val = x[(bc * HH + (yp - 1)) * WW + (xp - 1)];
    float q = rintf((val * 255.0f) / 16.0f);   // matches jnp.round(x*255/16), RNE
    q = fminf(fmaxf(q, 0.0f), 16.0f);
    v = (unsigned char)(int)q;
  }
  bins[idx] = v;
}

// ---------------- K2: mode pool 11x11 -> u8 mode bins [2,3,504,504] ----------------
__global__ __launch_bounds__(256) void k_mode(const unsigned char* __restrict__ bins,
                                              unsigned char* __restrict__ hmode) {
  __shared__ unsigned char tile[26 * 26];
  int bc  = blockIdx.z;
  int ty0 = blockIdx.y * 16, tx0 = blockIdx.x * 16;
  const unsigned char* src = bins + bc * HP * HP;
  for (int i = threadIdx.x; i < 26 * 26; i += 256) {
    int r = i / 26, cl = i % 26;
    int Y = ty0 + r, X = tx0 + cl;
    tile[i] = (Y < HP && X < HP) ? src[Y * HP + X] : (unsigned char)0;
  }
  __syncthreads();
  int ty = threadIdx.x >> 4, tx = threadIdx.x & 15;
  int oy = ty0 + ty, ox = tx0 + tx;
  if (oy >= HM || ox >= HM) return;
  unsigned long long w0 = 0, w1 = 0, w2 = 0;
  for (int dy = 0; dy < 11; dy++) {
    #pragma unroll
    for (int dx = 0; dx < 11; dx++) {
      int b = tile[(ty + dy) * 26 + tx + dx];
      unsigned long long inc = 1ull << ((b & 7) * 8);
      if (b < 8) w0 += inc;
      else if (b < 16) w1 += inc;
      else w2 += inc;
    }
  }
  int best = -1, bestb = 0;
  #pragma unroll
  for (int b = 0; b < 17; b++) {
    int cnt;
    if (b < 8)       cnt = (int)((w0 >> (b * 8)) & 0xff);
    else if (b < 16) cnt = (int)((w1 >> ((b - 8) * 8)) & 0xff);
    else             cnt = (int)(w2 & 0xff);
    if (cnt > best) { best = cnt; bestb = b; }   // strict > keeps lowest bin on tie
  }
  hmode[bc * HM * HM + oy * HM + ox] = (unsigned char)bestb;
}

// ---------------- K3: fused conv1+maxleaky + grouped conv2 + minleaky + downgrade ----------------
__global__ __launch_bounds__(256) void k_prepare(const unsigned char* __restrict__ hmode,
                                                 const float* __restrict__ w1,
                                                 const float* __restrict__ b1,
                                                 const float* __restrict__ w2,
                                                 const float* __restrict__ b2,
                                                 const float* __restrict__ down_k,
                                                 const float* __restrict__ down_b,
                                                 float* __restrict__ d1) {
  int bc = blockIdx.y;
  int b  = bc >> 6;
  int c  = bc & 63;
  int pix = blockIdx.x * 256 + threadIdx.x;
  if (pix >= 168 * 168) return;
  int oy = pix / 168, ox = pix % 168;
  int c0 = (c >> 1) << 1;
  float w1a0 = w1[c0 * 3], w1a1 = w1[c0 * 3 + 1], w1a2 = w1[c0 * 3 + 2], b1a = b1[c0];
  float w1b0 = w1[(c0 + 1) * 3], w1b1 = w1[(c0 + 1) * 3 + 1], w1b2 = w1[(c0 + 1) * 3 + 2], b1b = b1[c0 + 1];
  float w2a = w2[c * 2], w2b = w2[c * 2 + 1], b2c = b2[c];
  float kb = *down_b;
  const unsigned char* h0p = hmode + (b * 3 + 0) * HM * HM;
  const unsigned char* h1p = hmode + (b * 3 + 1) * HM * HM;
  const unsigned char* h2p = hmode + (b * 3 + 2) * HM * HM;
  float acc = 0.0f;
  #pragma unroll
  for (int ky = 0; ky < 3; ky++) {
    int y = 3 * oy - 1 + ky;
    if (y < 0 || y >= HM) continue;
    #pragma unroll
    for (int kx = 0; kx < 3; kx++) {
      int xx = 3 * ox - 1 + kx;
      if (xx < 0 || xx >= HM) continue;
      int o = y * HM + xx;
      float hh0 = h0p[o] * (1.0f / 16.0f);
      float hh1 = h1p[o] * (1.0f / 16.0f);
      float hh2 = h2p[o] * (1.0f / 16.0f);
      float a0 = w1a0 * hh0 + w1a1 * hh1 + w1a2 * hh2 + b1a;
      float a1 = w1b0 * hh0 + w1b1 * hh1 + w1b2 * hh2 + b1b;
      a0 = (a0 <= 0.1f) ? a0 : 0.1f + 0.01f * (a0 - 0.1f);
      a1 = (a1 <= 0.1f) ? a1 : 0.1f + 0.01f * (a1 - 0.1f);
      float v = w2a * a0 + w2b * a1 + b2c;
      v = (v >= 0.1f) ? v : 0.1f + 0.01f * (v - 0.1f);
      acc += down_k[ky * 3 + kx] * v;
    }
  }
  float r = acc + kb;
  r = (r >= 0.0f) ? r : 0.01f * r;
  d1[bc * 168 * 168 + pix] = r;
}

// ---------------- K4: generic downgrade (3x3 s3 p1 shared) + leaky ----------------
__global__ __launch_bounds__(256) void k_down(const float* __restrict__ din,
                                              float* __restrict__ dout,
                                              const float* __restrict__ down_k,
                                              const float* __restrict__ down_b,
                                              int S, int So) {
  int bc = blockIdx.y;
  int pix = blockIdx.x * 256 + threadIdx.x;
  if (pix >= So * So) return;
  int oy = pix / So, ox = pix % So;
  const float* p = din + bc * S * S;
  float acc = 0.0f;
  #pragma unroll
  for (int ky = 0; ky < 3; ky++) {
    int y = 3 * oy - 1 + ky;
    if (y < 0 || y >= S) continue;
    #pragma unroll
    for (int kx = 0; kx < 3; kx++) {
      int xx = 3 * ox - 1 + kx;
      if (xx < 0 || xx >= S) continue;
      acc += down_k[ky * 3 + kx] * p[y * S + xx];
    }
  }
  float r = acc + *down_b;
  r = (r >= 0.0f) ? r : 0.01f * r;
  dout[bc * So * So + pix] = r;
}

// ---------------- K_lut: bilinear LUT per level per coordinate ----------------
__global__ __launch_bounds__(256) void k_lut(int2* __restrict__ lut_i,
                                             float* __restrict__ lut_w) {
  int idx = blockIdx.x * 256 + threadIdx.x;   // 5*512
  if (idx >= 5 * 512) return;
  int lvl = idx >> 9, Y = idx & 511;
  const int Ls[5] = {168, 56, 19, 7, 3};
  int L = Ls[lvl];
  float f = (Y + 0.5f) * ((float)L / 512.0f) - 0.5f;
  f = fminf(fmaxf(f, 0.0f), (float)(L - 1));
  int y0 = (int)f;
  float w = f - (float)y0;
  int y1 = min(y0 + 1, L - 1);
  lut_i[idx] = make_int2(y0, y1);
  lut_w[idx] = w;
}

// ---------------- K5: fused 5-level resize + 5x5 shared conv + BN + leaky + sum ----------------
// Per block: (bc, 64x64 tile). All bilinear sources staged through LDS:
//   dt  : <=24x24 d-level tile (stride 25)
//   l*  : 68-entry per-axis LUT slices, r0/c0 pre-subtracted, row index pre-scaled by 25
//   z   : 68x68 upsampled plane for the 5x5 conv
__global__ __launch_bounds__(256, 2) void k_score(const float* __restrict__ d1,
                                                  const float* __restrict__ d2,
                                                  const float* __restrict__ d3,
                                                  const float* __restrict__ d4,
                                                  const float* __restrict__ d5,
                                                  const int2* __restrict__ lut_i,
                                                  const float* __restrict__ lut_w,
                                                  const float* __restrict__ interp_k,
                                                  const float* __restrict__ interp_b,
                                                  const float* __restrict__ i_gamma,
                                                  const float* __restrict__ i_beta,
                                                  const float* __restrict__ i_mean,
                                                  const float* __restrict__ i_var,
                                                  float* __restrict__ score) {
  __shared__ float z[68 * 68];
  __shared__ float dt[24 * 25];
  __shared__ int   ly0[68], ly1[68];
  __shared__ float lwy[68];
  __shared__ int   lx0[68], lx1[68];
  __shared__ float lwx[68];

  int bc = blockIdx.y;
  int c  = bc & 63;
  int tile = blockIdx.x;                    // 0..63
  int tyi = tile >> 3, txi = tile & 7;
  int ty0 = tyi * 64, tx0 = txi * 64;
  bool interior = (tyi >= 1 && tyi <= 6 && txi >= 1 && txi <= 6);
  float K[25];
  #pragma unroll
  for (int i = 0; i < 25; i++)
    K[i] = __int_as_float(__builtin_amdgcn_readfirstlane(__float_as_int(interp_k[i])));
  float ib  = __int_as_float(__builtin_amdgcn_readfirstlane(__float_as_int(*interp_b)));
  float isc = i_gamma[c] * rsqrtf(i_var[c] + 1e-5f);
  float ibe = i_beta[c] - i_mean[c] * isc;
  int tid = threadIdx.x;
  int oyl = (tid >> 4) << 2, oxl = (tid & 15) << 2; // 4x4 px per thread
  float acc[4][4];
  #pragma unroll
  for (int i = 0; i < 4; i++)
    #pragma unroll
    for (int j = 0; j < 4; j++) acc[i][j] = 0.0f;

  const float* dls[5] = {d1, d2, d3, d4, d5};
  const int Ls[5] = {168, 56, 19, 7, 3};

  #pragma unroll 1
  for (int lvl = 0; lvl < 5; lvl++) {
    const int L = Ls[lvl];
    const float* dp = dls[lvl] + bc * L * L;
    const int2*  li = lut_i + lvl * 512;
    const float* lw = lut_w + lvl * 512;
    // uniform source-region origin (LUT is monotone in the coordinate)
    int Ylo = max(ty0 - 2, 0), Xlo = max(tx0 - 2, 0);
    int r0 = li[Ylo].x;          // uniform -> scalar
    int c0 = li[Xlo].x;
    __syncthreads();             // previous level's conv reads of z/dt/lut done
    // stage LUT slices (r0/c0 folded in; row index pre-scaled by dt stride)
    if (tid < 68) {
      int Yc = min(max(ty0 - 2 + tid, 0), 511);
      int2 iy = li[Yc];
      ly0[tid] = (iy.x - r0) * 25;
      ly1[tid] = (iy.y - r0) * 25;
      lwy[tid] = lw[Yc];
    } else if (tid >= 128 && tid < 196) {
      int t = tid - 128;
      int Xc = min(max(tx0 - 2 + t, 0), 511);
      int2 ix = li[Xc];
      lx0[t] = ix.x - c0;
      lx1[t] = ix.y - c0;
      lwx[t] = lw[Xc];
    }
    // stage d-tile: 24x24 clamped region starting at (r0,c0), coalesced rows
    for (int i = tid; i < 576; i += 256) {
      int rr = i / 24, cc = i - rr * 24;
      int gr = min(r0 + rr, L - 1), gc = min(c0 + cc, L - 1);
      dt[rr * 25 + cc] = dp[gr * L + gc];
    }
    __syncthreads();
    // stage z from LDS only
    if (interior) {
      for (int i = tid; i < 68 * 68; i += 256) {
        int r = i / 68, cl = i - r * 68;
        int a0 = ly0[r], a1 = ly1[r]; float wy = lwy[r];
        int b0 = lx0[cl], b1 = lx1[cl]; float wx = lwx[cl];
        float v00 = dt[a0 + b0], v01 = dt[a0 + b1];
        float v10 = dt[a1 + b0], v11 = dt[a1 + b1];
        float top = v00 + wx * (v01 - v00);
        float bot = v10 + wx * (v11 - v10);
        z[i] = top + wy * (bot - top);
      }
    } else {
      for (int i = tid; i < 68 * 68; i += 256) {
        int r = i / 68, cl = i - r * 68;
        int Y = ty0 - 2 + r, X = tx0 - 2 + cl;
        float v = 0.0f;
        if (Y >= 0 && Y < 512 && X >= 0 && X < 512) {
          int a0 = ly0[r], a1 = ly1[r]; float wy = lwy[r];
          int b0 = lx0[cl], b1 = lx1[cl]; float wx = lwx[cl];
          float v00 = dt[a0 + b0], v01 = dt[a0 + b1];
          float v10 = dt[a1 + b0], v11 = dt[a1 + b1];
          float top = v00 + wx * (v01 - v00);
          float bot = v10 + wx * (v11 - v10);
          v = top + wy * (bot - top);
        }
        z[i] = v;
      }
    }
    __syncthreads();
    float tmp[4][4];
    #pragma unroll
    for (int i = 0; i < 4; i++)
      #pragma unroll
      for (int j = 0; j < 4; j++) tmp[i][j] = 0.0f;
    #pragma unroll
    for (int iy = 0; iy < 8; iy++) {
      const float4 za = *(const float4*)&z[(oyl + iy) * 68 + oxl];
      const float4 zb = *(const float4*)&z[(oyl + iy) * 68 + oxl + 4];
      float zr[8] = {za.x, za.y, za.z, za.w, zb.x, zb.y, zb.z, zb.w};
      #pragma unroll
      for (int ky = 0; ky < 5; ky++) {
        const int o = iy - ky;
        if (o >= 0 && o < 4) {
          #pragma unroll
          for (int ox = 0; ox < 4; ox++)
            #pragma unroll
            for (int kx = 0; kx < 5; kx++)
              tmp[o][ox] += K[ky * 5 + kx] * zr[ox + kx];
        }
      }
    }
    #pragma unroll
    for (int i = 0; i < 4; i++)
      #pragma unroll
      for (int j = 0; j < 4; j++) {
        float v = (tmp[i][j] + ib) * isc + ibe;
        v = (v >= 0.0f) ? v : 0.01f * v;
        acc[i][j] += v;
      }
  }
  float* op = score + bc * 512 * 512;
  #pragma unroll
  for (int i = 0; i < 4; i++) {
    int Y = ty0 + oyl + i;
    float4 vv = make_float4(acc[i][0], acc[i][1], acc[i][2], acc[i][3]);
    *(float4*)(op + Y * 512 + tx0 + oxl) = vv;
  }
}

// ---------------- K6: fused 3x ft (affine + 11x11 box emphase), LDS-tiled ----------------
// Tile: 64 rows x 32 cols output, halo 15 -> staged 94x62. A: s values; B: row sums.
#define FT_SA 63
#define FT_BW 53

template <int K>
__device__ __forceinline__ void ft_iter(float* Asm, float* Bsm, float w, float Aff, float Cc,
                                        int gy0, int gx0, float* out_g, int tid) {
  const int R0 = 5 * K;
  const int Rh = 94 - 10 * K;
  const int Ch = 52 - 10 * K;
  const int Cq = (Ch + 3) / 4;
  const int C0 = 5 * K + 5;
  for (int idx = tid; idx < Rh * Cq; idx += 256) {
    int r = idx / Cq, q = idx - r * Cq;
    int rr = R0 + r;
    int c0 = C0 + 4 * q;
    const float* ap = Asm + rr * FT_SA + (c0 - 5);
    float wv[14];
    #pragma unroll
    for (int j = 0; j < 14; j++) wv[j] = ap[j];
    float s0 = 0.0f;
    #pragma unroll
    for (int j = 0; j < 11; j++) s0 += wv[j];
    float s1 = s0 - wv[0] + wv[11];
    float s2 = s1 - wv[1] + wv[12];
    float s3 = s2 - wv[2] + wv[13];
    float* bp = Bsm + rr * FT_BW + 4 * q;
    int rem = Ch - 4 * q;
    bp[0] = s0;
    if (rem > 1) bp[1] = s1;
    if (rem > 2) bp[2] = s2;
    if (rem > 3) bp[3] = s3;
  }
  __syncthreads();
  const int Rv = 84 - 10 * K;
  const int Cv = Ch;
  const int Rq = (Rv + 3) / 4;
  for (int idx = tid; idx < Rq * Cv; idx += 256) {
    int rq = idx / Cv, cb = idx - rq * Cv;
    int r0 = C0 + 4 * rq;
    const float* bp = Bsm + (r0 - 5) * FT_BW + cb;
    float bv[14];
    #pragma unroll
    for (int j = 0; j < 14; j++) bv[j] = bp[j * FT_BW];
    float v0 = 0.0f;
    #pragma unroll
    for (int j = 0; j < 11; j++) v0 += bv[j];
    float v1 = v0 - bv[0] + bv[11];
    float v2 = v1 - bv[1] + bv[12];
    float v3 = v2 - bv[2] + bv[13];
    float vs[4] = {v0, v1, v2, v3};
    int rem = Rv - 4 * rq;
    int cc = C0 + cb;
    #pragma unroll
    for (int j = 0; j < 4; j++) {
      if (j < rem) {
        int rr = r0 + j;
        float s_c = Asm[rr * FT_SA + cc];
        float avg = vs[j] * (1.0f / 121.0f);
        float o = s_c + w * (s_c - avg);
        if (K < 2) {
          int gy = gy0 - 15 + rr, gx = gx0 - 15 + cc;
          bool in = (gy >= 0 && gy < 512 && gx >= 0 && gx < 512);
          Asm[rr * FT_SA + cc] = in ? (Aff * o + Cc) : 0.0f;
        } else {
          out_g[(gy0 - 15 + rr) * 512 + (gx0 - 15 + cc)] = o;
        }
      }
    }
  }
  __syncthreads();
}

__global__ __launch_bounds__(256) void k_ft(const float* __restrict__ s_in,
                                            float* __restrict__ s_out,
                                            const float* __restrict__ ft_gamma,
                                            const float* __restrict__ ft_beta,
                                            const float* __restrict__ ft_mean,
                                            const float* __restrict__ ft_var,
                                            const float* __restrict__ ft_k,
                                            const float* __restrict__ ft_b,
                                            const float* __restrict__ emph_w) {
  __shared__ float Asm[94 * FT_SA];
  __shared__ float Bsm[94 * FT_BW];
  int bc = blockIdx.y;
  int c  = bc & 63;
  int tile = blockIdx.x;                 // 16 x-tiles * 8 y-tiles
  int gx0 = (tile & 15) * 32;
  int gy0 = (tile >> 4) * 64;
  float sc = ft_gamma[c] * rsqrtf(ft_var[c] + 1e-5f);
  float fk = *ft_k, fb = *ft_b;
  float Aff = sc * fk;
  float Cc  = (ft_beta[c] - ft_mean[c] * sc) * fk + fb;
  float w   = emph_w[c];
  const float* sp = s_in + ((long long)bc << 18);
  float* op = s_out + ((long long)bc << 18);
  int tid = threadIdx.x;
  for (int i = tid; i < 94 * 62; i += 256) {
    int r = i / 62, cl = i - r * 62;
    int gy = gy0 - 15 + r, gx = gx0 - 15 + cl;
    float v = 0.0f;
    if (gy >= 0 && gy < 512 && gx >= 0 && gx < 512)
      v = Aff * sp[(gy << 9) + gx] + Cc;
    Asm[r * FT_SA + cl] = v;
  }
  __syncthreads();
  ft_iter<0>(Asm, Bsm, w, Aff, Cc, gy0, gx0, op, tid);
  ft_iter<1>(Asm, Bsm, w, Aff, Cc, gy0, gx0, op, tid);
  ft_iter<2>(Asm, Bsm, w, Aff, Cc, gy0, gx0, op, tid);
}

extern "C" void kernel_launch(void* const* d_in, const int* in_sizes, int n_in,
                              void* d_out, int out_size, void* d_ws, size_t ws_size,
                              hipStream_t stream) {
  const float* x        = (const float*)d_in[0];
  const float* w1       = (const float*)d_in[1];
  const float* b1       = (const float*)d_in[2];
  const float* w2       = (const float*)d_in[3];
  const float* b2       = (const float*)d_in[4];
  const float* down_k   = (const float*)d_in[5];
  const float* down_b   = (const float*)d_in[6];
  const float* ft_gamma = (const float*)d_in[7];
  const float* ft_beta  = (const float*)d_in[8];
  const float* ft_mean  = (const float*)d_in[9];
  const float* ft_var   = (const float*)d_in[10];
  const float* ft_k     = (const float*)d_in[11];
  const float* ft_b     = (const float*)d_in[12];
  const float* emph_w   = (const float*)d_in[13];
  const float* interp_k = (const float*)d_in[14];
  const float* interp_b = (const float*)d_in[15];
  const float* i_gamma  = (const float*)d_in[16];
  const float* i_beta   = (const float*)d_in[17];
  const float* i_mean   = (const float*)d_in[18];
  const float* i_var    = (const float*)d_in[19];
  float* out = (float*)d_out;                    // [2,64,512,512]

  char* ws = (char*)d_ws;
  size_t off = 0;
  auto alloc = [&](size_t bytes) { size_t r = off; off += (bytes + 255) & ~(size_t)255; return r; };
  unsigned char* bins  = (unsigned char*)(ws + alloc((size_t)NB * CIN * HP * HP));
  unsigned char* hmode = (unsigned char*)(ws + alloc((size_t)NB * CIN * HM * HM));
  float* d1 = (float*)(ws + alloc((size_t)NB * C2 * 168 * 168 * 4));
  float* d2 = (float*)(ws + alloc((size_t)NB * C2 * 56 * 56 * 4));
  float* d3 = (float*)(ws + alloc((size_t)NB * C2 * 19 * 19 * 4));
  float* d4 = (float*)(ws + alloc((size_t)NB * C2 * 7 * 7 * 4));
  float* d5 = (float*)(ws + alloc((size_t)NB * C2 * 3 * 3 * 4));
  float* s0 = (float*)(ws + alloc((size_t)NB * C2 * 512 * 512 * 4));  // pre-ft score
  int2*  lut_i = (int2*)(ws + alloc((size_t)5 * 512 * 8));
  float* lut_w = (float*)(ws + alloc((size_t)5 * 512 * 4));

  {
    int total = NB * CIN * HP * HP;
    k_quant<<<(total + 255) / 256, 256, 0, stream>>>(x, bins);
  }
  k_mode<<<dim3(32, 32, NB * CIN), 256, 0, stream>>>(bins, hmode);
  k_lut<<<10, 256, 0, stream>>>(lut_i, lut_w);
  k_prepare<<<dim3((168 * 168 + 255) / 256, NB * C2), 256, 0, stream>>>(
      hmode, w1, b1, w2, b2, down_k, down_b, d1);
  k_down<<<dim3((56 * 56 + 255) / 256, NB * C2), 256, 0, stream>>>(d1, d2, down_k, down_b, 168, 56);
  k_down<<<dim3((19 * 19 + 255) / 256, NB * C2), 256, 0, stream>>>(d2, d3, down_k, down_b, 56, 19);
  k_down<<<dim3((7 * 7 + 255) / 256, NB * C2), 256, 0, stream>>>(d3, d4, down_k, down_b, 19, 7);
  k_down<<<dim3((3 * 3 + 255) / 256, NB * C2), 256, 0, stream>>>(d4, d5, down_k, down_b, 7, 3);
  k_score<<<dim3(64, NB * C2), 256, 0, stream>>>(d1, d2, d3, d4, d5, lut_i, lut_w,
                                                 interp_k, interp_b,
                                                 i_gamma, i_beta, i_mean, i_var, s0);
  k_ft<<<dim3(128, NB * C2), 256, 0, stream>>>(s0, out, ft_gamma, ft_beta, ft_mean,
                                               ft_var, ft_k, ft_b, emph_w);
}

// Round 4
// 845.370 us; speedup vs baseline: 2.9699x; 1.0580x over previous
//
#include <hip/hip_runtime.h>

#define NB 2
#define CIN 3
#define HH 512
#define WW 512
#define C2 64
#define HM 504   // mode-pool output size

typedef float v2f  __attribute__((ext_vector_type(2)));
typedef float v2fu __attribute__((ext_vector_type(2), aligned(4)));

// ---------------- K2: quantize (inline) + mode pool 11x11 -> u8 [2,3,504,504] ----------------
__global__ __launch_bounds__(256) void k_mode(const float* __restrict__ x,
                                              unsigned char* __restrict__ hmode) {
  __shared__ unsigned char tile[26 * 26];
  int bc  = blockIdx.z;
  int ty0 = blockIdx.y * 16, tx0 = blockIdx.x * 16;
  const float* src = x + (size_t)bc * HH * WW;
  for (int i = threadIdx.x; i < 26 * 26; i += 256) {
    int r = i / 26, cl = i % 26;
    int Y = ty0 + r, X = tx0 + cl;      // padded coords (pad=1)
    unsigned char v = 0;
    if (Y >= 1 && Y <= HH && X >= 1 && X <= WW) {
      float val = src[(Y - 1) * WW + (X - 1)];
      float q = rintf((val * 255.0f) / 16.0f);   // matches jnp.round(x*255/16), RNE
      q = fminf(fmaxf(q, 0.0f), 16.0f);
      v = (unsigned char)(int)q;
    }
    tile[i] = v;
  }
  __syncthreads();
  int ty = threadIdx.x >> 4, tx = threadIdx.x & 15;
  int oy = ty0 + ty, ox = tx0 + tx;
  if (oy >= HM || ox >= HM) return;
  unsigned long long w0 = 0, w1 = 0, w2 = 0;
  for (int dy = 0; dy < 11; dy++) {
    #pragma unroll
    for (int dx = 0; dx < 11; dx++) {
      int b = tile[(ty + dy) * 26 + tx + dx];
      unsigned long long inc = 1ull << ((b & 7) * 8);
      if (b < 8) w0 += inc;
      else if (b < 16) w1 += inc;
      else w2 += inc;
    }
  }
  int best = -1, bestb = 0;
  #pragma unroll
  for (int b = 0; b < 17; b++) {
    int cnt;
    if (b < 8)       cnt = (int)((w0 >> (b * 8)) & 0xff);
    else if (b < 16) cnt = (int)((w1 >> ((b - 8) * 8)) & 0xff);
    else             cnt = (int)(w2 & 0xff);
    if (cnt > best) { best = cnt; bestb = b; }   // strict > keeps lowest bin on tie
  }
  hmode[bc * HM * HM + oy * HM + ox] = (unsigned char)bestb;
}

// ---------------- K3: fused conv1+maxleaky + grouped conv2 + minleaky + downgrade ----------------
__global__ __launch_bounds__(256) void k_prepare(const unsigned char* __restrict__ hmode,
                                                 const float* __restrict__ w1,
                                                 const float* __restrict__ b1,
                                                 const float* __restrict__ w2,
                                                 const float* __restrict__ b2,
                                                 const float* __restrict__ down_k,
                                                 const float* __restrict__ down_b,
                                                 float* __restrict__ d1) {
  int bc = blockIdx.y;
  int b  = bc >> 6;
  int c  = bc & 63;
  int pix = blockIdx.x * 256 + threadIdx.x;
  if (pix >= 168 * 168) return;
  int oy = pix / 168, ox = pix % 168;
  int c0 = (c >> 1) << 1;
  float w1a0 = w1[c0 * 3], w1a1 = w1[c0 * 3 + 1], w1a2 = w1[c0 * 3 + 2], b1a = b1[c0];
  float w1b0 = w1[(c0 + 1) * 3], w1b1 = w1[(c0 + 1) * 3 + 1], w1b2 = w1[(c0 + 1) * 3 + 2], b1b = b1[c0 + 1];
  float w2a = w2[c * 2], w2b = w2[c * 2 + 1], b2c = b2[c];
  float kb = *down_b;
  const unsigned char* h0p = hmode + (b * 3 + 0) * HM * HM;
  const unsigned char* h1p = hmode + (b * 3 + 1) * HM * HM;
  const unsigned char* h2p = hmode + (b * 3 + 2) * HM * HM;
  float acc = 0.0f;
  #pragma unroll
  for (int ky = 0; ky < 3; ky++) {
    int y = 3 * oy - 1 + ky;
    if (y < 0 || y >= HM) continue;
    #pragma unroll
    for (int kx = 0; kx < 3; kx++) {
      int xx = 3 * ox - 1 + kx;
      if (xx < 0 || xx >= HM) continue;
      int o = y * HM + xx;
      float hh0 = h0p[o] * (1.0f / 16.0f);
      float hh1 = h1p[o] * (1.0f / 16.0f);
      float hh2 = h2p[o] * (1.0f / 16.0f);
      float a0 = w1a0 * hh0 + w1a1 * hh1 + w1a2 * hh2 + b1a;
      float a1 = w1b0 * hh0 + w1b1 * hh1 + w1b2 * hh2 + b1b;
      a0 = (a0 <= 0.1f) ? a0 : 0.1f + 0.01f * (a0 - 0.1f);
      a1 = (a1 <= 0.1f) ? a1 : 0.1f + 0.01f * (a1 - 0.1f);
      float v = w2a * a0 + w2b * a1 + b2c;
      v = (v >= 0.1f) ? v : 0.1f + 0.01f * (v - 0.1f);
      acc += down_k[ky * 3 + kx] * v;
    }
  }
  float r = acc + kb;
  r = (r >= 0.0f) ? r : 0.01f * r;
  d1[bc * 168 * 168 + pix] = r;
}

// ---------------- K4: generic downgrade (3x3 s3 p1 shared) + leaky ----------------
__global__ __launch_bounds__(256) void k_down(const float* __restrict__ din,
                                              float* __restrict__ dout,
                                              const float* __restrict__ down_k,
                                              const float* __restrict__ down_b,
                                              int S, int So) {
  int bc = blockIdx.y;
  int pix = blockIdx.x * 256 + threadIdx.x;
  if (pix >= So * So) return;
  int oy = pix / So, ox = pix % So;
  const float* p = din + bc * S * S;
  float acc = 0.0f;
  #pragma unroll
  for (int ky = 0; ky < 3; ky++) {
    int y = 3 * oy - 1 + ky;
    if (y < 0 || y >= S) continue;
    #pragma unroll
    for (int kx = 0; kx < 3; kx++) {
      int xx = 3 * ox - 1 + kx;
      if (xx < 0 || xx >= S) continue;
      acc += down_k[ky * 3 + kx] * p[y * S + xx];
    }
  }
  float r = acc + *down_b;
  r = (r >= 0.0f) ? r : 0.01f * r;
  dout[bc * So * So + pix] = r;
}

// ---------------- K_lut: packed bilinear LUT {asfloat(y0), w} per level/coord ----------------
__global__ __launch_bounds__(256) void k_lut(float2* __restrict__ lutpk) {
  int idx = blockIdx.x * 256 + threadIdx.x;   // 5*512
  if (idx >= 5 * 512) return;
  int lvl = idx >> 9, Y = idx & 511;
  const int Ls[5] = {168, 56, 19, 7, 3};
  int L = Ls[lvl];
  float f = (Y + 0.5f) * ((float)L / 512.0f) - 0.5f;
  f = fminf(fmaxf(f, 0.0f), (float)(L - 1));
  int y0 = (int)f;
  float w = f - (float)y0;
  lutpk[idx] = make_float2(__int_as_float(y0), w);
}

// ---------------- K5: fused 5-level resize + 5x5 shared conv + BN + leaky + sum ----------------
// Two-phase separable resize through LDS:
//   phase A: rowIT[x][r] = x-interp of source row r at output col x  (from global d)
//   phase B: z[y][x]     = y-interp of rowIT pairs
// phase A of level l+1 is co-issued with conv(l) (disjoint LDS) to hide global latency.
__global__ __launch_bounds__(256, 2) void k_score(const float* __restrict__ d1,
                                                  const float* __restrict__ d2,
                                                  const float* __restrict__ d3,
                                                  const float* __restrict__ d4,
                                                  const float* __restrict__ d5,
                                                  const float2* __restrict__ lutpk,
                                                  const float* __restrict__ interp_k,
                                                  const float* __restrict__ interp_b,
                                                  const float* __restrict__ i_gamma,
                                                  const float* __restrict__ i_beta,
                                                  const float* __restrict__ i_mean,
                                                  const float* __restrict__ i_var,
                                                  float* __restrict__ score) {
  __shared__ float z[68 * 68];
  __shared__ float rowIT[68 * 25];     // transposed: [x][r], stride 25
  __shared__ float2 lyp[68];           // {asfloat(a0rel), wy}

  int bc = blockIdx.y;
  int c  = bc & 63;
  int tile = blockIdx.x;
  int tyi = tile >> 3, txi = tile & 7;
  int ty0 = tyi * 64, tx0 = txi * 64;
  bool interior = (tyi >= 1 && tyi <= 6 && txi >= 1 && txi <= 6);
  float K[25];
  #pragma unroll
  for (int i = 0; i < 25; i++)
    K[i] = __int_as_float(__builtin_amdgcn_readfirstlane(__float_as_int(interp_k[i])));
  float ib  = __int_as_float(__builtin_amdgcn_readfirstlane(__float_as_int(*interp_b)));
  float isc = i_gamma[c] * rsqrtf(i_var[c] + 1e-5f);
  float ibe = i_beta[c] - i_mean[c] * isc;
  int tid = threadIdx.x;
  int oyl = (tid >> 4) << 2, oxl = (tid & 15) << 2;  // 4x4 px per thread
  float acc[4][4];
  #pragma unroll
  for (int i = 0; i < 4; i++)
    #pragma unroll
    for (int j = 0; j < 4; j++) acc[i][j] = 0.0f;

  const float* dls[5] = {d1, d2, d3, d4, d5};
  const int Ls[5]  = {168, 56, 19, 7, 3};
  const int RLs[5] = {24, 10, 5, 3, 3};

  auto phaseA = [&](int l) {
    int L = Ls[l], R = RLs[l];
    const float* dp = dls[l] + bc * L * L;
    const float2* lp = lutpk + (l << 9);
    int Ylo = max(ty0 - 2, 0);
    int r0 = __float_as_int(lp[Ylo].x);
    if (tid < 68) {
      int Yc = min(max(ty0 - 2 + tid, 0), 511);
      float2 pk = lp[Yc];
      lyp[tid] = make_float2(__int_as_float(__float_as_int(pk.x) - r0), pk.y);
    }
    for (int i = tid; i < R * 68; i += 256) {
      int r = i / 68, xx = i - r * 68;
      int Xc = min(max(tx0 - 2 + xx, 0), 511);
      float2 pk = lp[Xc];
      int ix = __float_as_int(pk.x);
      float wx = pk.y;
      int gr = min(r0 + r, L - 1);
      const float* rp = dp + gr * L + ix;
      float v0 = rp[0], v1 = rp[1];       // v1 unused when wx==0 (clamp)
      rowIT[xx * 25 + r] = v0 + wx * (v1 - v0);
    }
  };

  auto phaseB = [&]() {
    if (interior) {
      for (int i = tid; i < 68 * 68; i += 256) {
        int yy = i / 68, xx = i - yy * 68;
        float2 pk = lyp[yy];
        int a0 = __float_as_int(pk.x);
        const float* rp = &rowIT[xx * 25 + a0];
        float rA = rp[0], rB = rp[1];
        z[i] = rA + pk.y * (rB - rA);
      }
    } else {
      for (int i = tid; i < 68 * 68; i += 256) {
        int yy = i / 68, xx = i - yy * 68;
        float2 pk = lyp[yy];
        int a0 = __float_as_int(pk.x);
        const float* rp = &rowIT[xx * 25 + a0];
        float rA = rp[0], rB = rp[1];
        float v = rA + pk.y * (rB - rA);
        int Y = ty0 - 2 + yy, X = tx0 - 2 + xx;
        if (Y < 0 || Y >= 512 || X < 0 || X >= 512) v = 0.0f;
        z[i] = v;
      }
    }
  };

  auto convAcc = [&]() {
    v2f t2[4][2];
    #pragma unroll
    for (int i = 0; i < 4; i++) { t2[i][0] = (v2f)0.0f; t2[i][1] = (v2f)0.0f; }
    #pragma unroll
    for (int iy = 0; iy < 8; iy++) {
      const float4 za = *(const float4*)&z[(oyl + iy) * 68 + oxl];
      const float4 zb = *(const float4*)&z[(oyl + iy) * 68 + oxl + 4];
      v2f qq[7];
      qq[0].x = za.x; qq[0].y = za.y;
      qq[1].x = za.y; qq[1].y = za.z;
      qq[2].x = za.z; qq[2].y = za.w;
      qq[3].x = za.w; qq[3].y = zb.x;
      qq[4].x = zb.x; qq[4].y = zb.y;
      qq[5].x = zb.y; qq[5].y = zb.z;
      qq[6].x = zb.z; qq[6].y = zb.w;
      #pragma unroll
      for (int ky = 0; ky < 5; ky++) {
        const int o = iy - ky;
        if (o >= 0 && o < 4) {
          #pragma unroll
          for (int kx = 0; kx < 5; kx++) {
            float kv = K[ky * 5 + kx];
            v2f kk; kk.x = kv; kk.y = kv;
            t2[o][0] += kk * qq[kx];
            t2[o][1] += kk * qq[kx + 2];
          }
        }
      }
    }
    #pragma unroll
    for (int i = 0; i < 4; i++) {
      float tv[4] = {t2[i][0].x, t2[i][0].y, t2[i][1].x, t2[i][1].y};
      #pragma unroll
      for (int j = 0; j < 4; j++) {
        float v = (tv[j] + ib) * isc + ibe;
        v = (v >= 0.0f) ? v : 0.01f * v;
        acc[i][j] += v;
      }
    }
  };

  phaseA(0);
  __syncthreads();
  phaseB();
  #pragma unroll 1
  for (int l = 0; l < 5; l++) {
    __syncthreads();                 // z(l) ready; rowIT/lyp consumed
    if (l < 4) phaseA(l + 1);        // global->rowIT, overlaps conv
    convAcc();                       // reads z(l)
    __syncthreads();                 // conv done with z; rowIT(l+1) ready
    if (l < 4) phaseB();             // rowIT->z(l+1)
  }

  float* op = score + bc * 512 * 512;
  #pragma unroll
  for (int i = 0; i < 4; i++) {
    int Y = ty0 + oyl + i;
    float4 vv = make_float4(acc[i][0], acc[i][1], acc[i][2], acc[i][3]);
    *(float4*)(op + Y * 512 + tx0 + oxl) = vv;
  }
}

// ---------------- K6: fused 3x ft (affine + 11x11 box emphase), LDS-tiled, paired LDS ops ----------------
#define FT_SA 63
#define FT_BW 53

template <int K>
__device__ __forceinline__ void ft_iter(float* Asm, float* Bsm, float w, float Aff, float Cc,
                                        int gy0, int gx0, float* out_g, int tid, bool tile_in) {
  // hsum: rows [5K, 94-5K), output cols [5K+5, 57-5K); B col c stored at (c-5)
  const int R0 = 5 * K, Rh = 94 - 10 * K;
  const int C0 = 5 * K + 5, Ch = 52 - 10 * K;
  const int Cq = (Ch + 3) >> 2;
  for (int idx = tid; idx < Rh * Cq; idx += 256) {
    int r = idx / Cq, q = idx - r * Cq;
    int rr = R0 + r;
    int cb = C0 + 4 * q;
    const float* ap = Asm + rr * FT_SA + (cb - 5);
    v2fu t0 = *(const v2fu*)(ap + 0);
    v2fu t1 = *(const v2fu*)(ap + 2);
    v2fu t2 = *(const v2fu*)(ap + 4);
    v2fu t3 = *(const v2fu*)(ap + 6);
    v2fu t4 = *(const v2fu*)(ap + 8);
    v2fu t5 = *(const v2fu*)(ap + 10);
    v2fu t6 = *(const v2fu*)(ap + 12);
    float s0 = ((t0.x + t0.y) + (t1.x + t1.y)) + ((t2.x + t2.y) + (t3.x + t3.y)) + ((t4.x + t4.y) + t5.x);
    float s1 = s0 - t0.x + t5.y;
    float s2 = s1 - t0.y + t6.x;
    float s3 = s2 - t1.x + t6.y;
    float* bp = Bsm + rr * FT_BW + (cb - 5);
    v2fu b0; b0.x = s0; b0.y = s1;
    v2fu b1; b1.x = s2; b1.y = s3;
    *(v2fu*)(bp) = b0;
    *(v2fu*)(bp + 2) = b1;
  }
  __syncthreads();
  // vsum + emphase update, 4x4 outputs per item: rows [5K+5, 89-5K), cols [5K+5, 57-5K)
  const int RV0 = C0, RVn = 84 - 10 * K;
  const int CV0 = C0, CVn = Ch;
  const int Rg = (RVn + 3) >> 2, Cg = (CVn + 3) >> 2;
  const int Rend = RV0 + RVn, Cend = CV0 + CVn;
  for (int idx = tid; idx < Rg * Cg; idx += 256) {
    int ri = idx / Cg, ci = idx - ri * Cg;
    int r4 = RV0 + 4 * ri, c4 = CV0 + 4 * ci;
    const float* bp = Bsm + (r4 - 5) * FT_BW + (c4 - 5);
    v2fu pA[14], pB[14];
    #pragma unroll
    for (int j = 0; j < 14; j++) {
      pA[j] = *(const v2fu*)(bp + j * FT_BW);
      pB[j] = *(const v2fu*)(bp + j * FT_BW + 2);
    }
    v2fu sA = pA[0], sB = pB[0];
    #pragma unroll
    for (int j = 1; j < 11; j++) { sA += pA[j]; sB += pB[j]; }
    v2fu vA[4], vB[4];
    vA[0] = sA; vB[0] = sB;
    #pragma unroll
    for (int j = 1; j < 4; j++) {
      vA[j] = vA[j - 1] - pA[j - 1] + pA[j + 10];
      vB[j] = vB[j - 1] - pB[j - 1] + pB[j + 10];
    }
    #pragma unroll
    for (int j = 0; j < 4; j++) {
      int rr = r4 + j;
      if (K != 1 || rr < Rend) {
        float* arow = Asm + rr * FT_SA + c4;
        v2fu a01 = *(const v2fu*)(arow);
        v2fu a23 = *(const v2fu*)(arow + 2);
        float e0 = a01.x + w * (a01.x - vA[j].x * (1.0f / 121.0f));
        float e1 = a01.y + w * (a01.y - vA[j].y * (1.0f / 121.0f));
        float e2 = a23.x + w * (a23.x - vB[j].x * (1.0f / 121.0f));
        float e3 = a23.y + w * (a23.y - vB[j].y * (1.0f / 121.0f));
        if (K < 2) {
          float n0 = Aff * e0 + Cc, n1 = Aff * e1 + Cc;
          float n2 = Aff * e2 + Cc, n3 = Aff * e3 + Cc;
          if (!tile_in) {
            int gy = gy0 - 15 + rr;
            int gxb = gx0 - 15 + c4;
            bool iny = (gy >= 0 && gy < 512);
            if (!(iny && gxb >= 0 && gxb < 512)) n0 = 0.0f;
            if (!(iny && gxb + 1 >= 0 && gxb + 1 < 512)) n1 = 0.0f;
            if (!(iny && gxb + 2 >= 0 && gxb + 2 < 512)) n2 = 0.0f;
            if (!(iny && gxb + 3 >= 0 && gxb + 3 < 512)) n3 = 0.0f;
          }
          v2fu w01; w01.x = n0; w01.y = n1;
          v2fu w23; w23.x = n2; w23.y = n3;
          bool ok2 = (K != 1) || (c4 + 2 < Cend);
          *(v2fu*)(arow) = w01;
          if (ok2) *(v2fu*)(arow + 2) = w23;
          else if (K == 1) { /* pair0 always valid (CVn even) */ }
        } else {
          // K==2: exact 64x32 core, always in-image; float4 global store
          float4 ov = make_float4(e0, e1, e2, e3);
          *(float4*)(out_g + (gy0 - 15 + rr) * 512 + gx0 + (c4 - 15)) = ov;
        }
      }
    }
  }
  __syncthreads();
}

__global__ __launch_bounds__(256) void k_ft(const float* __restrict__ s_in,
                                            float* __restrict__ s_out,
                                            const float* __restrict__ ft_gamma,
                                            const float* __restrict__ ft_beta,
                                            const float* __restrict__ ft_mean,
                                            const float* __restrict__ ft_var,
                                            const float* __restrict__ ft_k,
                                            const float* __restrict__ ft_b,
                                            const float* __restrict__ emph_w) {
  __shared__ float Asm[94 * FT_SA];
  __shared__ float Bsm[94 * FT_BW];
  int bc = blockIdx.y;
  int c  = bc & 63;
  int tile = blockIdx.x;                 // 16 x-tiles * 8 y-tiles
  int gx0 = (tile & 15) * 32;
  int gy0 = (tile >> 4) * 64;
  bool tile_in = (gy0 >= 16 && gy0 + 79 < 512 && gx0 >= 16 && gx0 + 47 < 512);
  float sc = ft_gamma[c] * rsqrtf(ft_var[c] + 1e-5f);
  float fk = *ft_k, fb = *ft_b;
  float Aff = sc * fk;
  float Cc  = (ft_beta[c] - ft_mean[c] * sc) * fk + fb;
  float w   = emph_w[c];
  const float* sp = s_in + ((long long)bc << 18);
  float* op = s_out + ((long long)bc << 18);
  int tid = threadIdx.x;
  for (int i = tid; i < 94 * 62; i += 256) {
    int r = i / 62, cl = i - r * 62;
    int gy = gy0 - 15 + r, gx = gx0 - 15 + cl;
    float v = 0.0f;
    if (gy >= 0 && gy < 512 && gx >= 0 && gx < 512)
      v = Aff * sp[(gy << 9) + gx] + Cc;
    Asm[r * FT_SA + cl] = v;
  }
  __syncthreads();
  ft_iter<0>(Asm, Bsm, w, Aff, Cc, gy0, gx0, op, tid, tile_in);
  ft_iter<1>(Asm, Bsm, w, Aff, Cc, gy0, gx0, op, tid, tile_in);
  ft_iter<2>(Asm, Bsm, w, Aff, Cc, gy0, gx0, op, tid, tile_in);
}

extern "C" void kernel_launch(void* const* d_in, const int* in_sizes, int n_in,
                              void* d_out, int out_size, void* d_ws, size_t ws_size,
                              hipStream_t stream) {
  const float* x        = (const float*)d_in[0];
  const float* w1       = (const float*)d_in[1];
  const float* b1       = (const float*)d_in[2];
  const float* w2       = (const float*)d_in[3];
  const float* b2       = (const float*)d_in[4];
  const float* down_k   = (const float*)d_in[5];
  const float* down_b   = (const float*)d_in[6];
  const float* ft_gamma = (const float*)d_in[7];
  const float* ft_beta  = (const float*)d_in[8];
  const float* ft_mean  = (const float*)d_in[9];
  const float* ft_var   = (const float*)d_in[10];
  const float* ft_k     = (const float*)d_in[11];
  const float* ft_b     = (const float*)d_in[12];
  const float* emph_w   = (const float*)d_in[13];
  const float* interp_k = (const float*)d_in[14];
  const float* interp_b = (const float*)d_in[15];
  const float* i_gamma  = (const float*)d_in[16];
  const float* i_beta   = (const float*)d_in[17];
  const float* i_mean   = (const float*)d_in[18];
  const float* i_var    = (const float*)d_in[19];
  float* out = (float*)d_out;                    // [2,64,512,512]

  char* ws = (char*)d_ws;
  size_t off = 0;
  auto alloc = [&](size_t bytes) { size_t r = off; off += (bytes + 255) & ~(size_t)255; return r; };
  unsigned char* hmode = (unsigned char*)(ws + alloc((size_t)NB * CIN * HM * HM));
  float* d1 = (float*)(ws + alloc((size_t)NB * C2 * 168 * 168 * 4));
  float* d2 = (float*)(ws + alloc((size_t)NB * C2 * 56 * 56 * 4));
  float* d3 = (float*)(ws + alloc((size_t)NB * C2 * 19 * 19 * 4));
  float* d4 = (float*)(ws + alloc((size_t)NB * C2 * 7 * 7 * 4));
  float* d5 = (float*)(ws + alloc((size_t)NB * C2 * 3 * 3 * 4));
  float* s0 = (float*)(ws + alloc((size_t)NB * C2 * 512 * 512 * 4));  // pre-ft score
  float2* lutpk = (float2*)(ws + alloc((size_t)5 * 512 * 8));

  k_mode<<<dim3(32, 32, NB * CIN), 256, 0, stream>>>(x, hmode);
  k_lut<<<10, 256, 0, stream>>>(lutpk);
  k_prepare<<<dim3((168 * 168 + 255) / 256, NB * C2), 256, 0, stream>>>(
      hmode, w1, b1, w2, b2, down_k, down_b, d1);
  k_down<<<dim3((56 * 56 + 255) / 256, NB * C2), 256, 0, stream>>>(d1, d2, down_k, down_b, 168, 56);
  k_down<<<dim3((19 * 19 + 255) / 256, NB * C2), 256, 0, stream>>>(d2, d3, down_k, down_b, 56, 19);
  k_down<<<dim3((7 * 7 + 255) / 256, NB * C2), 256, 0, stream>>>(d3, d4, down_k, down_b, 19, 7);
  k_down<<<dim3((3 * 3 + 255) / 256, NB * C2), 256, 0, stream>>>(d4, d5, down_k, down_b, 7, 3);
  k_score<<<dim3(64, NB * C2), 256, 0, stream>>>(d1, d2, d3, d4, d5, lutpk,
                                                 interp_k, interp_b,
                                                 i_gamma, i_beta, i_mean, i_var, s0);
  k_ft<<<dim3(128, NB * C2), 256, 0, stream>>>(s0, out, ft_gamma, ft_beta, ft_mean,
                                               ft_var, ft_k, ft_b, emph_w);
}